// Round 6
// baseline (908.552 us; speedup 1.0000x reference)
//
#include <hip/hip_runtime.h>
#include <hip/hip_bf16.h>

#define NN   50000
#define EE   1600000
#define FIN  128
#define FOUT 64
#define BETA  0.5f
#define ALPHA 0.2f

#define BW     64            // src rows per bucket
#define NB     782           // ceil(NN/BW)
#define PGRID  128           // partition blocks
#define PCHUNK 12500         // EE/PGRID exact
#define HGRID  400           // hist blocks
#define HCHUNK 4000          // EE/HGRID exact

// Read element i of a buffer that is either fp32 (isf32=1) or bf16 (isf32=0).
__device__ __forceinline__ float load_any(const void* p, long i, int isf32) {
    if (isf32) return ((const float*)p)[i];
    unsigned int b = ((unsigned int)(((const unsigned short*)p)[i])) << 16;
    return __uint_as_float(b);
}

__device__ __forceinline__ unsigned short f32_to_bf16_rne(float f) {
    unsigned int b = __float_as_uint(f);
    return (unsigned short)((b + 0x7FFF + ((b >> 16) & 1)) >> 16);
}

__device__ __forceinline__ float bf16_to_f32(unsigned short u) {
    return __uint_as_float(((unsigned int)u) << 16);
}

// ---------------------------------------------------------------------------
// Kernel 0: sampled dtype detection. flags[t]=1 means fp32.
// ---------------------------------------------------------------------------
__global__ __launch_bounds__(256) void detect_kernel(
    const void* inp, const void* Mv, const void* W, const void* a, int* flags)
{
    const void* ptrs[4] = { inp, Mv, W, a };
    const long  cnts[4] = { (long)NN * FIN, (long)EE, (long)FIN * FOUT, 2L * FOUT };
    const int t = blockIdx.x;
    const unsigned short* p = (const unsigned short*)ptrs[t];
    const long half = cnts[t] >> 1;
    long step = half / 256; if (step == 0) step = 1;
    const long pos = 2 * (((long)threadIdx.x * step) % half);

    const float v = bf16_to_f32(p[pos]);
    const int bad = (isnan(v) || fabsf(v) > 1e4f) ? 1 : 0;

    __shared__ int sbad[256];
    sbad[threadIdx.x] = bad;
    __syncthreads();
    for (int s = 128; s > 0; s >>= 1) {
        if (threadIdx.x < (unsigned)s) sbad[threadIdx.x] |= sbad[threadIdx.x + s];
        __syncthreads();
    }
    if (threadIdx.x == 0) flags[t] = sbad[0];
}

// ---------------------------------------------------------------------------
// Kernel 1: h = X @ W (fp32 accum, stored bf16), fused s1/s2 projections.
// ---------------------------------------------------------------------------
__global__ __launch_bounds__(256) void gemm_proj_kernel(
    const void* __restrict__ inp,
    const void* __restrict__ W,
    const void* __restrict__ a,
    const int* __restrict__ flags,
    unsigned short* __restrict__ h,
    float* __restrict__ s1,
    float* __restrict__ s2)
{
    __shared__ float Ws[FIN * FOUT];   // 32 KB
    __shared__ float rows[16][FIN];    // 8 KB

    const int tid  = threadIdx.x;
    const int wave = tid >> 6;
    const int lane = tid & 63;
    const int rbase = blockIdx.x * 16;

    const int fI = flags[0], fW = flags[2], fA = flags[3];

    for (int i = tid; i < FIN * FOUT; i += 256)
        Ws[i] = load_any(W, i, fW);

    for (int i = tid; i < 16 * FIN; i += 256) {
        const int r = i >> 7, c = i & 127;
        rows[r][c] = load_any(inp, (long)(rbase + r) * FIN + c, fI);
    }
    __syncthreads();

    const int r0 = wave * 4;
    float a0 = 0.f, a1 = 0.f, a2 = 0.f, a3 = 0.f;
    #pragma unroll 8
    for (int k = 0; k < FIN; ++k) {
        const float w = Ws[k * FOUT + lane];
        a0 = fmaf(rows[r0 + 0][k], w, a0);
        a1 = fmaf(rows[r0 + 1][k], w, a1);
        a2 = fmaf(rows[r0 + 2][k], w, a2);
        a3 = fmaf(rows[r0 + 3][k], w, a3);
    }

    const int row = rbase + r0;
    h[(long)(row + 0) * FOUT + lane] = f32_to_bf16_rne(a0);
    h[(long)(row + 1) * FOUT + lane] = f32_to_bf16_rne(a1);
    h[(long)(row + 2) * FOUT + lane] = f32_to_bf16_rne(a2);
    h[(long)(row + 3) * FOUT + lane] = f32_to_bf16_rne(a3);

    const float av1 = load_any(a, lane, fA);
    const float av2 = load_any(a, lane + 64, fA);
    float accs[4] = { a0, a1, a2, a3 };
    #pragma unroll
    for (int r = 0; r < 4; ++r) {
        float v1 = accs[r] * av1;
        float v2 = accs[r] * av2;
        #pragma unroll
        for (int off = 32; off > 0; off >>= 1) {
            v1 += __shfl_down(v1, off, 64);
            v2 += __shfl_down(v2, off, 64);
        }
        if (lane == 0) { s1[row + r] = v1; s2[row + r] = v2; }
    }
}

// ---------------------------------------------------------------------------
// Kernel 2: bucket histogram (bucket = src >> 6). LDS-staged.
// ---------------------------------------------------------------------------
__global__ __launch_bounds__(256) void bucket_hist_kernel(
    const int* __restrict__ edge, int* __restrict__ bcnt)
{
    __shared__ int cnt[NB];
    for (int i = threadIdx.x; i < NB; i += 256) cnt[i] = 0;
    __syncthreads();
    const int e0 = blockIdx.x * HCHUNK;
    for (int e = e0 + threadIdx.x; e < e0 + HCHUNK; e += 256)
        atomicAdd(&cnt[edge[e] >> 6], 1);
    __syncthreads();
    for (int i = threadIdx.x; i < NB; i += 256)
        if (cnt[i]) atomicAdd(&bcnt[i], cnt[i]);
}

// ---------------------------------------------------------------------------
// Kernel 3: exclusive scan of bcnt[NB] -> base[NB+1]; cursor = base.
// One block of 1024 threads (NB=782 <= 1024).
// ---------------------------------------------------------------------------
__global__ __launch_bounds__(1024) void bucket_scan_kernel(
    const int* __restrict__ bcnt, int* __restrict__ base, int* __restrict__ cursor)
{
    const int tid = threadIdx.x, wave = tid >> 6, lane = tid & 63;
    const int c = (tid < NB) ? bcnt[tid] : 0;
    int x = c;
    #pragma unroll
    for (int off = 1; off < 64; off <<= 1) {
        int y = __shfl_up(x, off, 64);
        if (lane >= off) x += y;
    }
    __shared__ int wsum[16];
    if (lane == 63) wsum[wave] = x;
    __syncthreads();
    int wb = 0;
    for (int w = 0; w < wave; ++w) wb += wsum[w];
    if (tid < NB) {
        const int v = wb + x - c;
        base[tid]   = v;
        cursor[tid] = v;
    }
    if (tid == 0) base[NB] = EE;
}

// ---------------------------------------------------------------------------
// Kernel 4: partition. Per block: LDS-count its chunk, reserve ONE contiguous
// run per bucket (single global atomic), then append records. All record
// writes are to freshly-reserved contiguous runs (~16 rec = 128 B) filled
// within the block's lifetime -> writeback ~= essential bytes, no positioned
// scatter anywhere. Record u64: src<<32 | dst<<16 | bf16(edge_e).
// ---------------------------------------------------------------------------
__global__ __launch_bounds__(256) void partition_kernel(
    const int* __restrict__ edge,
    const void* __restrict__ Mv,
    const int* __restrict__ flags,
    const float* __restrict__ s1,
    const float* __restrict__ s2,
    int* __restrict__ cursor,
    unsigned long long* __restrict__ recs)
{
    __shared__ int lcnt[NB];
    __shared__ int lbase[NB];
    const int tid = threadIdx.x;
    const int fM = flags[1];
    const int e0 = blockIdx.x * PCHUNK;

    for (int i = tid; i < NB; i += 256) lcnt[i] = 0;
    __syncthreads();

    for (int e = e0 + tid; e < e0 + PCHUNK; e += 256)
        atomicAdd(&lcnt[edge[e] >> 6], 1);
    __syncthreads();

    for (int i = tid; i < NB; i += 256) {
        const int c = lcnt[i];
        lbase[i] = c ? atomicAdd(&cursor[i], c) : 0;
        lcnt[i] = 0;                 // reuse as rank counter
    }
    __syncthreads();

    for (int e = e0 + tid; e < e0 + PCHUNK; e += 256) {
        const int src = edge[e];
        const int dst = edge[EE + e];
        const float bias = load_any(Mv, e, fM) * BETA + (1.f - BETA);
        const float x  = s1[src] + bias * s2[dst];
        const float lr = x > 0.f ? x : ALPHA * x;
        const float ee = __expf(lr);
        const int b = src >> 6;
        const int r = atomicAdd(&lcnt[b], 1);
        recs[lbase[b] + r] = ((unsigned long long)(unsigned)src << 32)
                           | ((unsigned long long)(unsigned)dst << 16)
                           | (unsigned long long)f32_to_bf16_rne(ee);
    }
}

// ---------------------------------------------------------------------------
// Kernel 5: bucket-SpMM with fused finalize. One block per bucket; fp32
// accumulator tile (64 rows x 64 feats = 16 KB) + rowsum in LDS; stream the
// bucket's records, gather h[dst] (128 B/wave, L2/LLC-hot), ds_add_f32
// accumulate; then out = elu(acc/rowsum).
// ---------------------------------------------------------------------------
__global__ __launch_bounds__(256) void bucket_spmm_kernel(
    const int* __restrict__ base,
    const unsigned long long* __restrict__ recs,
    const unsigned short* __restrict__ h,   // bf16 [NN, FOUT]
    const int* __restrict__ flags,
    void* __restrict__ out)
{
    __shared__ float acc[BW * FOUT];   // 16 KB
    __shared__ float rsum[BW];
    const int b    = blockIdx.x;
    const int tid  = threadIdx.x;
    const int wave = tid >> 6;
    const int lane = tid & 63;

    for (int i = tid; i < BW * FOUT; i += 256) acc[i] = 0.f;
    if (tid < BW) rsum[tid] = 0.f;
    __syncthreads();

    const int beg = base[b];
    const int end = base[b + 1];
    const int rowbase = b * BW;

    for (int j = beg + wave * 4; j < end; j += 16) {
        const int m = end - j;          // >= 1
        unsigned long long rr[4];
        rr[0] = recs[j];
        #pragma unroll
        for (int k = 1; k < 4; ++k) rr[k] = (k < m) ? recs[j + k] : rr[0];

        float gv[4], ev[4];
        int   sl[4];
        #pragma unroll
        for (int k = 0; k < 4; ++k) {
            const int dst = (int)((rr[k] >> 16) & 0xFFFF);
            gv[k] = bf16_to_f32(h[(long)dst * FOUT + lane]);
            ev[k] = bf16_to_f32((unsigned short)(rr[k] & 0xFFFF));
            sl[k] = (int)(rr[k] >> 32) - rowbase;
        }
        #pragma unroll
        for (int k = 0; k < 4; ++k) {
            if (k < m) {
                atomicAdd(&acc[sl[k] * FOUT + lane], ev[k] * gv[k]);
                if (lane == 0) atomicAdd(&rsum[sl[k]], ev[k]);
            }
        }
    }
    __syncthreads();

    const int isf32 = flags[0];
    for (int r = wave; r < BW; r += 4) {
        const int row = rowbase + r;
        if (row >= NN) break;
        const float inv = 1.f / rsum[r];
        float q = acc[r * FOUT + lane] * inv;
        q = q > 0.f ? q : (__expf(q) - 1.f);
        if (isf32) ((float*)out)[(long)row * FOUT + lane] = q;
        else ((unsigned short*)out)[(long)row * FOUT + lane] = f32_to_bf16_rne(q);
    }
}

extern "C" void kernel_launch(void* const* d_in, const int* in_sizes, int n_in,
                              void* d_out, int out_size, void* d_ws, size_t ws_size,
                              hipStream_t stream) {
    const void* inp  = d_in[0];
    const void* Mv   = d_in[1];
    const void* W    = d_in[2];
    const void* a    = d_in[3];
    const int*  edge = (const int*)d_in[4];

    // ws: flags | h bf16[NN*64] | s1[NN] | s2[NN] | bcnt[NB] | base[NB+1] |
    //     cursor[NB] | recs u64[EE]
    char* p = (char*)d_ws;
    int*                flags  = (int*)p;            p += 256;
    unsigned short*     h      = (unsigned short*)p; p += ((size_t)NN * FOUT * 2 + 255) / 256 * 256;
    float*              s1     = (float*)p;          p += ((size_t)NN * 4 + 255) / 256 * 256;
    float*              s2     = (float*)p;          p += ((size_t)NN * 4 + 255) / 256 * 256;
    int*                bcnt   = (int*)p;            p += ((size_t)NB * 4 + 255) / 256 * 256;
    int*                base   = (int*)p;            p += ((size_t)(NB + 1) * 4 + 255) / 256 * 256;
    int*                cursor = (int*)p;            p += ((size_t)NB * 4 + 255) / 256 * 256;
    unsigned long long* recs   = (unsigned long long*)p;

    detect_kernel<<<4, 256, 0, stream>>>(inp, Mv, W, a, flags);
    hipMemsetAsync(bcnt, 0, (size_t)NB * sizeof(int), stream);
    gemm_proj_kernel<<<NN / 16, 256, 0, stream>>>(inp, W, a, flags, h, s1, s2);
    bucket_hist_kernel<<<HGRID, 256, 0, stream>>>(edge, bcnt);
    bucket_scan_kernel<<<1, 1024, 0, stream>>>(bcnt, base, cursor);
    partition_kernel<<<PGRID, 256, 0, stream>>>(edge, Mv, flags, s1, s2, cursor, recs);
    bucket_spmm_kernel<<<NB, 256, 0, stream>>>(base, recs, h, flags, d_out);
}

// Round 7
// 319.871 us; speedup vs baseline: 2.8404x; 2.8404x over previous
//
#include <hip/hip_runtime.h>
#include <hip/hip_bf16.h>

#define NN   50000
#define EE   1600000
#define FIN  128
#define FOUT 64
#define BETA  0.5f
#define ALPHA 0.2f
#define NCHUNK 196          // ceil(NN/256) for row-scan
#define BW     64           // src rows per bucket
#define NB     782          // ceil(NN/BW)
#define PGRID  400          // partition blocks
#define PCHUNK 4000         // EE/PGRID exact

// Read element i of a buffer that is either fp32 (isf32=1) or bf16 (isf32=0).
__device__ __forceinline__ float load_any(const void* p, long i, int isf32) {
    if (isf32) return ((const float*)p)[i];
    unsigned int b = ((unsigned int)(((const unsigned short*)p)[i])) << 16;
    return __uint_as_float(b);
}

__device__ __forceinline__ unsigned short f32_to_bf16_rne(float f) {
    unsigned int b = __float_as_uint(f);
    return (unsigned short)((b + 0x7FFF + ((b >> 16) & 1)) >> 16);
}

__device__ __forceinline__ float bf16_to_f32(unsigned short u) {
    return __uint_as_float(((unsigned int)u) << 16);
}

// ---------------------------------------------------------------------------
// Kernel 0: sampled dtype detection. flags[t]=1 means fp32.
// ---------------------------------------------------------------------------
__global__ __launch_bounds__(256) void detect_kernel(
    const void* inp, const void* Mv, const void* W, const void* a, int* flags)
{
    const void* ptrs[4] = { inp, Mv, W, a };
    const long  cnts[4] = { (long)NN * FIN, (long)EE, (long)FIN * FOUT, 2L * FOUT };
    const int t = blockIdx.x;
    const unsigned short* p = (const unsigned short*)ptrs[t];
    const long half = cnts[t] >> 1;
    long step = half / 256; if (step == 0) step = 1;
    const long pos = 2 * (((long)threadIdx.x * step) % half);

    const float v = bf16_to_f32(p[pos]);
    const int bad = (isnan(v) || fabsf(v) > 1e4f) ? 1 : 0;

    __shared__ int sbad[256];
    sbad[threadIdx.x] = bad;
    __syncthreads();
    for (int s = 128; s > 0; s >>= 1) {
        if (threadIdx.x < (unsigned)s) sbad[threadIdx.x] |= sbad[threadIdx.x + s];
        __syncthreads();
    }
    if (threadIdx.x == 0) flags[t] = sbad[0];
}

// ---------------------------------------------------------------------------
// Kernel 1: h = X @ W (fp32 accum, stored bf16), fused s1/s2 projections.
// ---------------------------------------------------------------------------
__global__ __launch_bounds__(256) void gemm_proj_kernel(
    const void* __restrict__ inp,
    const void* __restrict__ W,
    const void* __restrict__ a,
    const int* __restrict__ flags,
    unsigned short* __restrict__ h,
    float* __restrict__ s1,
    float* __restrict__ s2)
{
    __shared__ float Ws[FIN * FOUT];   // 32 KB
    __shared__ float rows[16][FIN];    // 8 KB

    const int tid  = threadIdx.x;
    const int wave = tid >> 6;
    const int lane = tid & 63;
    const int rbase = blockIdx.x * 16;

    const int fI = flags[0], fW = flags[2], fA = flags[3];

    for (int i = tid; i < FIN * FOUT; i += 256)
        Ws[i] = load_any(W, i, fW);

    for (int i = tid; i < 16 * FIN; i += 256) {
        const int r = i >> 7, c = i & 127;
        rows[r][c] = load_any(inp, (long)(rbase + r) * FIN + c, fI);
    }
    __syncthreads();

    const int r0 = wave * 4;
    float a0 = 0.f, a1 = 0.f, a2 = 0.f, a3 = 0.f;
    #pragma unroll 8
    for (int k = 0; k < FIN; ++k) {
        const float w = Ws[k * FOUT + lane];
        a0 = fmaf(rows[r0 + 0][k], w, a0);
        a1 = fmaf(rows[r0 + 1][k], w, a1);
        a2 = fmaf(rows[r0 + 2][k], w, a2);
        a3 = fmaf(rows[r0 + 3][k], w, a3);
    }

    const int row = rbase + r0;
    h[(long)(row + 0) * FOUT + lane] = f32_to_bf16_rne(a0);
    h[(long)(row + 1) * FOUT + lane] = f32_to_bf16_rne(a1);
    h[(long)(row + 2) * FOUT + lane] = f32_to_bf16_rne(a2);
    h[(long)(row + 3) * FOUT + lane] = f32_to_bf16_rne(a3);

    const float av1 = load_any(a, lane, fA);
    const float av2 = load_any(a, lane + 64, fA);
    float accs[4] = { a0, a1, a2, a3 };
    #pragma unroll
    for (int r = 0; r < 4; ++r) {
        float v1 = accs[r] * av1;
        float v2 = accs[r] * av2;
        #pragma unroll
        for (int off = 32; off > 0; off >>= 1) {
            v1 += __shfl_down(v1, off, 64);
            v2 += __shfl_down(v2, off, 64);
        }
        if (lane == 0) { s1[row + r] = v1; s2[row + r] = v2; }
    }
}

// ---------------------------------------------------------------------------
// Per-row histogram + 3-kernel scan -> rowptr[NN+1]; scan3 also seeds the
// per-bucket append cursor bcur[b] = rowptr[b*64].
// ---------------------------------------------------------------------------
__global__ __launch_bounds__(256) void hist_kernel(
    const int* __restrict__ edge, int* __restrict__ counts)
{
    const int e = blockIdx.x * 256 + threadIdx.x;
    if (e < EE) atomicAdd(&counts[edge[e]], 1);
}

__global__ __launch_bounds__(256) void scan1_kernel(
    const int* __restrict__ counts, int* __restrict__ rowptr, int* __restrict__ bsums)
{
    const int tid = threadIdx.x, wave = tid >> 6, lane = tid & 63;
    const int i = blockIdx.x * 256 + tid;
    const int c = (i < NN) ? counts[i] : 0;
    int x = c;
    #pragma unroll
    for (int off = 1; off < 64; off <<= 1) {
        int y = __shfl_up(x, off, 64);
        if (lane >= off) x += y;
    }
    __shared__ int wsum[4];
    if (lane == 63) wsum[wave] = x;
    __syncthreads();
    int wb = 0;
    for (int w = 0; w < wave; ++w) wb += wsum[w];
    if (i < NN) rowptr[i] = wb + x - c;
    if (tid == 255) bsums[blockIdx.x] = wb + x;
}

__global__ __launch_bounds__(256) void scan2_kernel(
    int* __restrict__ bsums, int* __restrict__ boffs)
{
    const int tid = threadIdx.x, wave = tid >> 6, lane = tid & 63;
    const int c = (tid < NCHUNK) ? bsums[tid] : 0;
    int x = c;
    #pragma unroll
    for (int off = 1; off < 64; off <<= 1) {
        int y = __shfl_up(x, off, 64);
        if (lane >= off) x += y;
    }
    __shared__ int wsum[4];
    if (lane == 63) wsum[wave] = x;
    __syncthreads();
    int wb = 0;
    for (int w = 0; w < wave; ++w) wb += wsum[w];
    if (tid < NCHUNK) boffs[tid] = wb + x - c;
}

__global__ __launch_bounds__(256) void scan3_kernel(
    int* __restrict__ rowptr, const int* __restrict__ boffs, int* __restrict__ bcur)
{
    const int i = blockIdx.x * 256 + threadIdx.x;
    if (i < NN) {
        const int v = rowptr[i] + boffs[blockIdx.x];
        rowptr[i] = v;
        if ((i & (BW - 1)) == 0) bcur[i >> 6] = v;   // bucket append cursor
    }
    if (i == 0) rowptr[NN] = EE;
}

// ---------------------------------------------------------------------------
// Phase A: partition. Per block: LDS-count its chunk per bucket, reserve ONE
// contiguous run per bucket (single global atomic on bcur), append u64 recs.
// All stores land in freshly-reserved contiguous runs filled within the
// block's lifetime -> writeback ~= essential bytes.
// Record: src<<32 | dst<<16 | bf16(edge_e).
// ---------------------------------------------------------------------------
__global__ __launch_bounds__(256) void partition_kernel(
    const int* __restrict__ edge,
    const void* __restrict__ Mv,
    const int* __restrict__ flags,
    const float* __restrict__ s1,
    const float* __restrict__ s2,
    int* __restrict__ bcur,
    unsigned long long* __restrict__ recs)
{
    __shared__ int lcnt[NB];
    __shared__ int lbase[NB];
    const int tid = threadIdx.x;
    const int fM = flags[1];
    const int e0 = blockIdx.x * PCHUNK;

    for (int i = tid; i < NB; i += 256) lcnt[i] = 0;
    __syncthreads();

    for (int e = e0 + tid; e < e0 + PCHUNK; e += 256)
        atomicAdd(&lcnt[edge[e] >> 6], 1);
    __syncthreads();

    for (int i = tid; i < NB; i += 256) {
        const int c = lcnt[i];
        lbase[i] = c ? atomicAdd(&bcur[i], c) : 0;
        lcnt[i] = 0;                 // reuse as rank counter
    }
    __syncthreads();

    for (int e = e0 + tid; e < e0 + PCHUNK; e += 256) {
        const int src = edge[e];
        const int dst = edge[EE + e];
        const float bias = load_any(Mv, e, fM) * BETA + (1.f - BETA);
        const float x  = s1[src] + bias * s2[dst];
        const float lr = x > 0.f ? x : ALPHA * x;
        const float ee = __expf(lr);
        const int b = src >> 6;
        const int r = atomicAdd(&lcnt[b], 1);
        recs[lbase[b] + r] = ((unsigned long long)(unsigned)src << 32)
                           | ((unsigned long long)(unsigned)dst << 16)
                           | (unsigned long long)f32_to_bf16_rne(ee);
    }
}

// ---------------------------------------------------------------------------
// Phase B: within-bucket CSR finalize. One block per bucket: read the
// bucket's contiguous rec segment, rank per row via LDS counters, write the
// 4B packed pair at rowptr[src]+rank. The destination segment is the
// bucket's contiguous ~8 KB CSR slice, written densely -> no write amp.
// ---------------------------------------------------------------------------
__global__ __launch_bounds__(256) void bucket_csr_kernel(
    const int* __restrict__ rowptr,
    const unsigned long long* __restrict__ recs,
    unsigned int* __restrict__ pairs)
{
    __shared__ int lrp[BW];   // rowptr slice
    __shared__ int lrk[BW];   // rank counters
    const int b   = blockIdx.x;
    const int tid = threadIdx.x;
    const int rb  = b * BW;

    if (tid < BW) {
        const int row = rb + tid;
        lrp[tid] = (row < NN) ? rowptr[row] : EE;
        lrk[tid] = 0;
    }
    __syncthreads();

    const int beg = lrp[0];
    const int end = (rb + BW <= NN) ? rowptr[rb + BW] : EE;

    for (int j = beg + tid; j < end; j += 256) {
        const unsigned long long rec = recs[j];
        const int r = (int)(rec >> 32) - rb;
        const int rank = atomicAdd(&lrk[r], 1);
        pairs[lrp[r] + rank] = (unsigned int)(rec & 0xFFFFFFFFu);
    }
}

// ---------------------------------------------------------------------------
// CSR-vector SpMM, fused finalize. One wave per src row; 32 lanes per edge
// (ushort2 = 2 features/lane), 2 edges in flight per half, unrolled x8
// (16 edges/iteration, 8 gathers in flight per half-wave).
// ---------------------------------------------------------------------------
__global__ __launch_bounds__(256) void spmm_kernel(
    const int* __restrict__ rowptr,
    const unsigned int* __restrict__ pairs,
    const unsigned short* __restrict__ h,   // bf16 [NN, FOUT]
    const int* __restrict__ flags,
    void* __restrict__ out)
{
    const int wave = threadIdx.x >> 6;
    const int lane = threadIdx.x & 63;
    const int half = lane >> 5;
    const int sl   = lane & 31;
    const int row  = blockIdx.x * 4 + wave;

    const int beg = rowptr[row];
    const int end = rowptr[row + 1];

    float acc0 = 0.f, acc1 = 0.f, rsum = 0.f;
    int j = beg;
    for (; j + 15 < end; j += 16) {
        unsigned int u[8];
        ushort2 hv[8];
        #pragma unroll
        for (int k = 0; k < 8; ++k) u[k] = pairs[j + 2 * k + half];
        #pragma unroll
        for (int k = 0; k < 8; ++k)
            hv[k] = *(const ushort2*)&h[(long)(u[k] >> 16) * FOUT + 2 * sl];
        #pragma unroll
        for (int k = 0; k < 8; ++k) {
            const float v = bf16_to_f32((unsigned short)u[k]);
            rsum += v;
            acc0 = fmaf(v, bf16_to_f32(hv[k].x), acc0);
            acc1 = fmaf(v, bf16_to_f32(hv[k].y), acc1);
        }
    }
    for (; j + 1 < end; j += 2) {
        const unsigned int u = pairs[j + half];
        const ushort2 hv = *(const ushort2*)&h[(long)(u >> 16) * FOUT + 2 * sl];
        const float v = bf16_to_f32((unsigned short)u);
        rsum += v;
        acc0 = fmaf(v, bf16_to_f32(hv.x), acc0);
        acc1 = fmaf(v, bf16_to_f32(hv.y), acc1);
    }
    if (j < end && half == 0) {
        const unsigned int u = pairs[j];
        const ushort2 hv = *(const ushort2*)&h[(long)(u >> 16) * FOUT + 2 * sl];
        const float v = bf16_to_f32((unsigned short)u);
        rsum += v;
        acc0 = fmaf(v, bf16_to_f32(hv.x), acc0);
        acc1 = fmaf(v, bf16_to_f32(hv.y), acc1);
    }

    acc0 += __shfl_xor(acc0, 32, 64);
    acc1 += __shfl_xor(acc1, 32, 64);
    rsum += __shfl_xor(rsum, 32, 64);

    if (half == 0) {
        const float inv = 1.f / rsum;
        float q0 = acc0 * inv;
        float q1 = acc1 * inv;
        q0 = q0 > 0.f ? q0 : (__expf(q0) - 1.f);
        q1 = q1 > 0.f ? q1 : (__expf(q1) - 1.f);
        if (flags[0]) {
            float2* o = (float2*)((float*)out + (long)row * FOUT + 2 * sl);
            *o = make_float2(q0, q1);
        } else {
            ushort2* o = (ushort2*)((unsigned short*)out + (long)row * FOUT + 2 * sl);
            *o = make_ushort2(f32_to_bf16_rne(q0), f32_to_bf16_rne(q1));
        }
    }
}

extern "C" void kernel_launch(void* const* d_in, const int* in_sizes, int n_in,
                              void* d_out, int out_size, void* d_ws, size_t ws_size,
                              hipStream_t stream) {
    const void* inp  = d_in[0];
    const void* Mv   = d_in[1];
    const void* W    = d_in[2];
    const void* a    = d_in[3];
    const int*  edge = (const int*)d_in[4];

    // ws: flags | h bf16[NN*64] | s1[NN] | s2[NN] | counts[NN] | rowptr[NN+1] |
    //     bcur[NB] | bsums[NCHUNK] | boffs[NCHUNK] | pairs u32[EE] | recs u64[EE]
    char* p = (char*)d_ws;
    int*                flags  = (int*)p;            p += 256;
    unsigned short*     h      = (unsigned short*)p; p += ((size_t)NN * FOUT * 2 + 255) / 256 * 256;
    float*              s1     = (float*)p;          p += ((size_t)NN * 4 + 255) / 256 * 256;
    float*              s2     = (float*)p;          p += ((size_t)NN * 4 + 255) / 256 * 256;
    int*                counts = (int*)p;            p += ((size_t)NN * 4 + 255) / 256 * 256;
    int*                rowptr = (int*)p;            p += ((size_t)(NN + 1) * 4 + 255) / 256 * 256;
    int*                bcur   = (int*)p;            p += ((size_t)NB * 4 + 255) / 256 * 256;
    int*                bsums  = (int*)p;            p += (NCHUNK * 4 + 255) / 256 * 256;
    int*                boffs  = (int*)p;            p += (NCHUNK * 4 + 255) / 256 * 256;
    unsigned int*       pairs  = (unsigned int*)p;   p += ((size_t)EE * 4 + 255) / 256 * 256;
    unsigned long long* recs   = (unsigned long long*)p;

    detect_kernel<<<4, 256, 0, stream>>>(inp, Mv, W, a, flags);
    hipMemsetAsync(counts, 0, (size_t)NN * sizeof(int), stream);
    gemm_proj_kernel<<<NN / 16, 256, 0, stream>>>(inp, W, a, flags, h, s1, s2);
    hist_kernel<<<(EE + 255) / 256, 256, 0, stream>>>(edge, counts);
    scan1_kernel<<<NCHUNK, 256, 0, stream>>>(counts, rowptr, bsums);
    scan2_kernel<<<1, 256, 0, stream>>>(bsums, boffs);
    scan3_kernel<<<NCHUNK, 256, 0, stream>>>(rowptr, boffs, bcur);
    partition_kernel<<<PGRID, 256, 0, stream>>>(edge, Mv, flags, s1, s2, bcur, recs);
    bucket_csr_kernel<<<NB, 256, 0, stream>>>(rowptr, recs, pairs);
    spmm_kernel<<<NN / 4, 256, 0, stream>>>(rowptr, pairs, h, flags, d_out);
}

// Round 8
// 255.170 us; speedup vs baseline: 3.5606x; 1.2536x over previous
//
#include <hip/hip_runtime.h>
#include <hip/hip_bf16.h>

#define NN   50000
#define EE   1600000
#define FIN  128
#define FOUT 64
#define BETA  0.5f
#define ALPHA 0.2f
#define BW     64           // src rows per bucket
#define NB     782          // ceil(NN/BW)
#define PGRID  400          // partition blocks
#define PCHUNK 4000         // EE/PGRID exact
#define HGRID  400          // bucket-hist blocks
#define HCHUNK 4000         // EE/HGRID exact
#define CAP    4096         // bucket_csr LDS record cache (recs); fallback if exceeded

// Read element i of a buffer that is either fp32 (isf32=1) or bf16 (isf32=0).
__device__ __forceinline__ float load_any(const void* p, long i, int isf32) {
    if (isf32) return ((const float*)p)[i];
    unsigned int b = ((unsigned int)(((const unsigned short*)p)[i])) << 16;
    return __uint_as_float(b);
}

__device__ __forceinline__ unsigned short f32_to_bf16_rne(float f) {
    unsigned int b = __float_as_uint(f);
    return (unsigned short)((b + 0x7FFF + ((b >> 16) & 1)) >> 16);
}

__device__ __forceinline__ float bf16_to_f32(unsigned short u) {
    return __uint_as_float(((unsigned int)u) << 16);
}

// ---------------------------------------------------------------------------
// Kernel 0: sampled dtype detection. flags[t]=1 means fp32.
// ---------------------------------------------------------------------------
__global__ __launch_bounds__(256) void detect_kernel(
    const void* inp, const void* Mv, const void* W, const void* a, int* flags)
{
    const void* ptrs[4] = { inp, Mv, W, a };
    const long  cnts[4] = { (long)NN * FIN, (long)EE, (long)FIN * FOUT, 2L * FOUT };
    const int t = blockIdx.x;
    const unsigned short* p = (const unsigned short*)ptrs[t];
    const long half = cnts[t] >> 1;
    long step = half / 256; if (step == 0) step = 1;
    const long pos = 2 * (((long)threadIdx.x * step) % half);

    const float v = bf16_to_f32(p[pos]);
    const int bad = (isnan(v) || fabsf(v) > 1e4f) ? 1 : 0;

    __shared__ int sbad[256];
    sbad[threadIdx.x] = bad;
    __syncthreads();
    for (int s = 128; s > 0; s >>= 1) {
        if (threadIdx.x < (unsigned)s) sbad[threadIdx.x] |= sbad[threadIdx.x + s];
        __syncthreads();
    }
    if (threadIdx.x == 0) flags[t] = sbad[0];
}

// ---------------------------------------------------------------------------
// Kernel 1: h = X @ W (fp32 accum, stored bf16), fused s1/s2 projections.
// ---------------------------------------------------------------------------
__global__ __launch_bounds__(256) void gemm_proj_kernel(
    const void* __restrict__ inp,
    const void* __restrict__ W,
    const void* __restrict__ a,
    const int* __restrict__ flags,
    unsigned short* __restrict__ h,
    float* __restrict__ s1,
    float* __restrict__ s2)
{
    __shared__ float Ws[FIN * FOUT];   // 32 KB
    __shared__ float rows[16][FIN];    // 8 KB

    const int tid  = threadIdx.x;
    const int wave = tid >> 6;
    const int lane = tid & 63;
    const int rbase = blockIdx.x * 16;

    const int fI = flags[0], fW = flags[2], fA = flags[3];

    for (int i = tid; i < FIN * FOUT; i += 256)
        Ws[i] = load_any(W, i, fW);

    for (int i = tid; i < 16 * FIN; i += 256) {
        const int r = i >> 7, c = i & 127;
        rows[r][c] = load_any(inp, (long)(rbase + r) * FIN + c, fI);
    }
    __syncthreads();

    const int r0 = wave * 4;
    float a0 = 0.f, a1 = 0.f, a2 = 0.f, a3 = 0.f;
    #pragma unroll 8
    for (int k = 0; k < FIN; ++k) {
        const float w = Ws[k * FOUT + lane];
        a0 = fmaf(rows[r0 + 0][k], w, a0);
        a1 = fmaf(rows[r0 + 1][k], w, a1);
        a2 = fmaf(rows[r0 + 2][k], w, a2);
        a3 = fmaf(rows[r0 + 3][k], w, a3);
    }

    const int row = rbase + r0;
    h[(long)(row + 0) * FOUT + lane] = f32_to_bf16_rne(a0);
    h[(long)(row + 1) * FOUT + lane] = f32_to_bf16_rne(a1);
    h[(long)(row + 2) * FOUT + lane] = f32_to_bf16_rne(a2);
    h[(long)(row + 3) * FOUT + lane] = f32_to_bf16_rne(a3);

    const float av1 = load_any(a, lane, fA);
    const float av2 = load_any(a, lane + 64, fA);
    float accs[4] = { a0, a1, a2, a3 };
    #pragma unroll
    for (int r = 0; r < 4; ++r) {
        float v1 = accs[r] * av1;
        float v2 = accs[r] * av2;
        #pragma unroll
        for (int off = 32; off > 0; off >>= 1) {
            v1 += __shfl_down(v1, off, 64);
            v2 += __shfl_down(v2, off, 64);
        }
        if (lane == 0) { s1[row + r] = v1; s2[row + r] = v2; }
    }
}

// ---------------------------------------------------------------------------
// Kernel 2: bucket histogram (bucket = src >> 6), LDS-staged: only NB*HGRID
// global atomics total (vs 1.6M scattered per-row atomics -> 50 MB RMW amp).
// ---------------------------------------------------------------------------
__global__ __launch_bounds__(256) void bucket_hist_kernel(
    const int* __restrict__ edge, int* __restrict__ bcnt)
{
    __shared__ int cnt[NB];
    for (int i = threadIdx.x; i < NB; i += 256) cnt[i] = 0;
    __syncthreads();
    const int e0 = blockIdx.x * HCHUNK;
    for (int e = e0 + threadIdx.x; e < e0 + HCHUNK; e += 256)
        atomicAdd(&cnt[edge[e] >> 6], 1);
    __syncthreads();
    for (int i = threadIdx.x; i < NB; i += 256)
        if (cnt[i]) atomicAdd(&bcnt[i], cnt[i]);
}

// ---------------------------------------------------------------------------
// Kernel 3: exclusive scan of bcnt[NB] -> base[NB+1]; bcur = base.
// ---------------------------------------------------------------------------
__global__ __launch_bounds__(1024) void bucket_scan_kernel(
    const int* __restrict__ bcnt, int* __restrict__ base, int* __restrict__ bcur)
{
    const int tid = threadIdx.x, wave = tid >> 6, lane = tid & 63;
    const int c = (tid < NB) ? bcnt[tid] : 0;
    int x = c;
    #pragma unroll
    for (int off = 1; off < 64; off <<= 1) {
        int y = __shfl_up(x, off, 64);
        if (lane >= off) x += y;
    }
    __shared__ int wsum[16];
    if (lane == 63) wsum[wave] = x;
    __syncthreads();
    int wb = 0;
    for (int w = 0; w < wave; ++w) wb += wsum[w];
    if (tid < NB) {
        const int v = wb + x - c;
        base[tid] = v;
        bcur[tid] = v;
    }
    if (tid == 0) base[NB] = EE;
}

// ---------------------------------------------------------------------------
// Kernel 4: partition. Per block: LDS-count its chunk per bucket, reserve ONE
// contiguous run per bucket (single global atomic on bcur), append u64 recs.
// All stores land in freshly-reserved contiguous runs filled within the
// block's lifetime -> writeback ~= essential bytes.
// Record: src<<32 | dst<<16 | bf16(edge_e).
// ---------------------------------------------------------------------------
__global__ __launch_bounds__(256) void partition_kernel(
    const int* __restrict__ edge,
    const void* __restrict__ Mv,
    const int* __restrict__ flags,
    const float* __restrict__ s1,
    const float* __restrict__ s2,
    int* __restrict__ bcur,
    unsigned long long* __restrict__ recs)
{
    __shared__ int lcnt[NB];
    __shared__ int lbase[NB];
    const int tid = threadIdx.x;
    const int fM = flags[1];
    const int e0 = blockIdx.x * PCHUNK;

    for (int i = tid; i < NB; i += 256) lcnt[i] = 0;
    __syncthreads();

    for (int e = e0 + tid; e < e0 + PCHUNK; e += 256)
        atomicAdd(&lcnt[edge[e] >> 6], 1);
    __syncthreads();

    for (int i = tid; i < NB; i += 256) {
        const int c = lcnt[i];
        lbase[i] = c ? atomicAdd(&bcur[i], c) : 0;
        lcnt[i] = 0;                 // reuse as rank counter
    }
    __syncthreads();

    for (int e = e0 + tid; e < e0 + PCHUNK; e += 256) {
        const int src = edge[e];
        const int dst = edge[EE + e];
        const float bias = load_any(Mv, e, fM) * BETA + (1.f - BETA);
        const float x  = s1[src] + bias * s2[dst];
        const float lr = x > 0.f ? x : ALPHA * x;
        const float ee = __expf(lr);
        const int b = src >> 6;
        const int r = atomicAdd(&lcnt[b], 1);
        recs[lbase[b] + r] = ((unsigned long long)(unsigned)src << 32)
                           | ((unsigned long long)(unsigned)dst << 16)
                           | (unsigned long long)f32_to_bf16_rne(ee);
    }
}

// ---------------------------------------------------------------------------
// Kernel 5: within-bucket CSR finalize + rowptr derivation. One block per
// bucket: cache the bucket's rec segment in LDS (global fallback if > CAP),
// count per-row in LDS, wave-scan -> rowptr slice (dense write), then
// rank-and-write 4B pairs into the bucket's contiguous CSR slice.
// ---------------------------------------------------------------------------
__global__ __launch_bounds__(256) void bucket_csr_kernel(
    const int* __restrict__ base,
    const unsigned long long* __restrict__ recs,
    unsigned int* __restrict__ pairs,
    int* __restrict__ rowptr)
{
    __shared__ unsigned long long lrec[CAP];   // 32 KB
    __shared__ int cnt[BW];
    __shared__ int off[BW];
    const int b   = blockIdx.x;
    const int tid = threadIdx.x;
    const int rb  = b * BW;

    const int beg = base[b];
    const int end = base[b + 1];
    const int n   = end - beg;
    const bool fits = (n <= CAP);

    if (tid < BW) cnt[tid] = 0;
    __syncthreads();

    for (int j = tid; j < n; j += 256) {
        const unsigned long long rec = recs[beg + j];
        if (fits) lrec[j] = rec;
        atomicAdd(&cnt[(int)(rec >> 32) - rb], 1);
    }
    __syncthreads();

    if (tid < BW) {   // single wave: exclusive scan of 64 counters
        const int c = cnt[tid];
        int x = c;
        #pragma unroll
        for (int o = 1; o < 64; o <<= 1) {
            int y = __shfl_up(x, o, 64);
            if ((tid & 63) >= o) x += y;
        }
        off[tid] = x - c;
        const int row = rb + tid;
        if (row < NN) rowptr[row] = beg + x - c;
        cnt[tid] = 0;  // reuse as rank counters
    }
    if (b == NB - 1 && tid == 0) rowptr[NN] = EE;
    __syncthreads();

    for (int j = tid; j < n; j += 256) {
        const unsigned long long rec = fits ? lrec[j] : recs[beg + j];
        const int r = (int)(rec >> 32) - rb;
        const int rank = atomicAdd(&cnt[r], 1);
        pairs[beg + off[r] + rank] = (unsigned int)(rec & 0xFFFFFFFFu);
    }
}

// ---------------------------------------------------------------------------
// Kernel 6: CSR-vector SpMM, fused finalize. One wave per src row; 32 lanes
// per edge (ushort2 = 2 features/lane), 2 edges in flight per half,
// unrolled x8 (16 edges/iteration).
// ---------------------------------------------------------------------------
__global__ __launch_bounds__(256) void spmm_kernel(
    const int* __restrict__ rowptr,
    const unsigned int* __restrict__ pairs,
    const unsigned short* __restrict__ h,   // bf16 [NN, FOUT]
    const int* __restrict__ flags,
    void* __restrict__ out)
{
    const int wave = threadIdx.x >> 6;
    const int lane = threadIdx.x & 63;
    const int half = lane >> 5;
    const int sl   = lane & 31;
    const int row  = blockIdx.x * 4 + wave;

    const int beg = rowptr[row];
    const int end = rowptr[row + 1];

    float acc0 = 0.f, acc1 = 0.f, rsum = 0.f;
    int j = beg;
    for (; j + 15 < end; j += 16) {
        unsigned int u[8];
        ushort2 hv[8];
        #pragma unroll
        for (int k = 0; k < 8; ++k) u[k] = pairs[j + 2 * k + half];
        #pragma unroll
        for (int k = 0; k < 8; ++k)
            hv[k] = *(const ushort2*)&h[(long)(u[k] >> 16) * FOUT + 2 * sl];
        #pragma unroll
        for (int k = 0; k < 8; ++k) {
            const float v = bf16_to_f32((unsigned short)u[k]);
            rsum += v;
            acc0 = fmaf(v, bf16_to_f32(hv[k].x), acc0);
            acc1 = fmaf(v, bf16_to_f32(hv[k].y), acc1);
        }
    }
    for (; j + 1 < end; j += 2) {
        const unsigned int u = pairs[j + half];
        const ushort2 hv = *(const ushort2*)&h[(long)(u >> 16) * FOUT + 2 * sl];
        const float v = bf16_to_f32((unsigned short)u);
        rsum += v;
        acc0 = fmaf(v, bf16_to_f32(hv.x), acc0);
        acc1 = fmaf(v, bf16_to_f32(hv.y), acc1);
    }
    if (j < end && half == 0) {
        const unsigned int u = pairs[j];
        const ushort2 hv = *(const ushort2*)&h[(long)(u >> 16) * FOUT + 2 * sl];
        const float v = bf16_to_f32((unsigned short)u);
        rsum += v;
        acc0 = fmaf(v, bf16_to_f32(hv.x), acc0);
        acc1 = fmaf(v, bf16_to_f32(hv.y), acc1);
    }

    acc0 += __shfl_xor(acc0, 32, 64);
    acc1 += __shfl_xor(acc1, 32, 64);
    rsum += __shfl_xor(rsum, 32, 64);

    if (half == 0) {
        const float inv = 1.f / rsum;
        float q0 = acc0 * inv;
        float q1 = acc1 * inv;
        q0 = q0 > 0.f ? q0 : (__expf(q0) - 1.f);
        q1 = q1 > 0.f ? q1 : (__expf(q1) - 1.f);
        if (flags[0]) {
            float2* o = (float2*)((float*)out + (long)row * FOUT + 2 * sl);
            *o = make_float2(q0, q1);
        } else {
            ushort2* o = (ushort2*)((unsigned short*)out + (long)row * FOUT + 2 * sl);
            *o = make_ushort2(f32_to_bf16_rne(q0), f32_to_bf16_rne(q1));
        }
    }
}

extern "C" void kernel_launch(void* const* d_in, const int* in_sizes, int n_in,
                              void* d_out, int out_size, void* d_ws, size_t ws_size,
                              hipStream_t stream) {
    const void* inp  = d_in[0];
    const void* Mv   = d_in[1];
    const void* W    = d_in[2];
    const void* a    = d_in[3];
    const int*  edge = (const int*)d_in[4];

    // ws: flags | h bf16[NN*64] | s1[NN] | s2[NN] | rowptr[NN+1] | bcnt[NB] |
    //     base[NB+1] | bcur[NB] | pairs u32[EE] | recs u64[EE]
    char* p = (char*)d_ws;
    int*                flags  = (int*)p;            p += 256;
    unsigned short*     h      = (unsigned short*)p; p += ((size_t)NN * FOUT * 2 + 255) / 256 * 256;
    float*              s1     = (float*)p;          p += ((size_t)NN * 4 + 255) / 256 * 256;
    float*              s2     = (float*)p;          p += ((size_t)NN * 4 + 255) / 256 * 256;
    int*                rowptr = (int*)p;            p += ((size_t)(NN + 1) * 4 + 255) / 256 * 256;
    int*                bcnt   = (int*)p;            p += ((size_t)NB * 4 + 255) / 256 * 256;
    int*                base   = (int*)p;            p += ((size_t)(NB + 1) * 4 + 255) / 256 * 256;
    int*                bcur   = (int*)p;            p += ((size_t)NB * 4 + 255) / 256 * 256;
    unsigned int*       pairs  = (unsigned int*)p;   p += ((size_t)EE * 4 + 255) / 256 * 256;
    unsigned long long* recs   = (unsigned long long*)p;

    detect_kernel<<<4, 256, 0, stream>>>(inp, Mv, W, a, flags);
    hipMemsetAsync(bcnt, 0, (size_t)NB * sizeof(int), stream);
    gemm_proj_kernel<<<NN / 16, 256, 0, stream>>>(inp, W, a, flags, h, s1, s2);
    bucket_hist_kernel<<<HGRID, 256, 0, stream>>>(edge, bcnt);
    bucket_scan_kernel<<<1, 1024, 0, stream>>>(bcnt, base, bcur);
    partition_kernel<<<PGRID, 256, 0, stream>>>(edge, Mv, flags, s1, s2, bcur, recs);
    bucket_csr_kernel<<<NB, 256, 0, stream>>>(base, recs, pairs, rowptr);
    spmm_kernel<<<NN / 4, 256, 0, stream>>>(rowptr, pairs, h, flags, d_out);
}